// Round 8
// baseline (592.884 us; speedup 1.0000x reference)
//
#include <hip/hip_runtime.h>
#include <cstdint>
#include <cstdio>

#define DEVINL __device__ __forceinline__

typedef _Float16 f16x8 __attribute__((ext_vector_type(8)));
typedef float    f32x4 __attribute__((ext_vector_type(4)));

static constexpr int B_  = 8;
static constexpr int C_  = 1024;
static constexpr int CI_ = 512;
static constexpr int N_  = 56 * 56;   // 3136
static constexpr int NP  = 3328;      // padded to multiple of 256
static constexpr float BN_EPS = 1e-5f;

DEVINL uint16_t f2h(float f) {
  union { _Float16 h; uint16_t u; } cv;
  cv.h = (_Float16)f;   // RNE
  return cv.u;
}

DEVINL void async16(const void* g, void* lds) {
  __builtin_amdgcn_global_load_lds(
      (const __attribute__((address_space(1))) uint32_t*)g,
      (__attribute__((address_space(3))) uint32_t*)lds, 16, 0, 0);
}

// ---------------------------------------------------------------------------
// 256x256 8-phase TN GEMM (m201 template, fp16 in / fp16 out, fp32 acc).
// C[m,n] = sum_k A[m,k]*Bt[n,k] (+bias). M%256==0, N%256==0, K%64==0.
// 512 threads = 8 waves (2M x 4N); per-wave output 128x64; acc[8][4] f32x4.
// LDS 128KB: A/B x 2 bufs x 2 k-slices(32) of [256][32] fp16.
// Swizzle: 16B chunk c within row: phys = c ^ ((row>>1)&3) (both sides;
// verified r5: bank conflicts 8.3M -> 0). Counted vmcnt(8) only; per-phase
// barrier + lgkmcnt(0) + sched_barrier(0). BIAS: 0 none, 1 per-row, 2 per-col.
// colMajor: 1 -> by varies fastest over consecutive wgid (A-panel reuse).
// C stores are NON-TEMPORAL: outputs are read only by later dispatches; keep
// them out of L2 so staging panels stay resident (r7 analysis: f is
// cache-BW-bound; C-write streams were thrashing the ~4MB panel working set).
// ---------------------------------------------------------------------------
template <int BIAS>
__global__ __launch_bounds__(512, 2) void gemm256(
    const uint16_t* __restrict__ A, const uint16_t* __restrict__ Bt,
    uint16_t* __restrict__ Cc, const float* __restrict__ bias,
    int K, int lda, int ldb, int ldc,
    long aBatch, long bBatch, long cBatch, int nbx, int nby, int colMajor) {
  __shared__ uint16_t lds[65536];   // 128 KiB

  // bijective XCD swizzle (m204)
  const int nwg = gridDim.x, orig = blockIdx.x;
  const int q = nwg >> 3, r = nwg & 7, xcd = orig & 7, idx = orig >> 3;
  const int wgid = (xcd < r ? xcd * (q + 1) : r * (q + 1) + (xcd - r) * q) + idx;
  const int rest = wgid % (nbx * nby);
  const int bx = colMajor ? rest / nby : rest % nbx;
  const int by = colMajor ? rest % nby : rest / nbx;
  const int zb = wgid / (nbx * nby);

  const int tid = threadIdx.x, w = tid >> 6, l = tid & 63;
  const int wm = w >> 2, wn = w & 3, lr = l & 15, lg = l >> 4;

  const uint16_t* Ab = A + (long)zb * aBatch + (long)bx * 256 * lda;
  const uint16_t* Bb = Bt + (long)zb * bBatch + (long)by * 256 * ldb;

  const int NT = K >> 6;

  // staging: half-tile = [256 rows][32 k] fp16 = 1024 chunks of 16B, 2 instrs.
  // chunk c: row=c>>2, source col pre-swizzled: col16 = (c&3) ^ ((c>>3)&3)
  const int c0 = tid, c1 = 512 + tid;
  const long aoff0 = (long)(c0 >> 2) * lda + (((c0 & 3) ^ ((c0 >> 3) & 3)) * 8);
  const long aoff1 = (long)(c1 >> 2) * lda + (((c1 & 3) ^ ((c1 >> 3) & 3)) * 8);
  const long boff0 = (long)(c0 >> 2) * ldb + (((c0 & 3) ^ ((c0 >> 3) & 3)) * 8);
  const long boff1 = (long)(c1 >> 2) * ldb + (((c1 & 3) ^ ((c1 >> 3) & 3)) * 8);
  const int ldsW0 = (w * 64) * 8;          // wave-uniform dest (elems), instr 0
  const int ldsW1 = (512 + w * 64) * 8;    // instr 1

  auto stageA = [&](int t, int ks, int buf) {
    int tw = t; while (tw >= NT) tw -= NT;   // wrap: garbage, never computed
    const uint16_t* src = Ab + tw * 64 + ks * 32;
    const int reg = (buf * 2 + ks) * 8192;
    async16(src + aoff0, &lds[reg + ldsW0]);
    async16(src + aoff1, &lds[reg + ldsW1]);
  };
  auto stageB = [&](int t, int ks, int buf) {
    int tw = t; while (tw >= NT) tw -= NT;
    const uint16_t* src = Bb + tw * 64 + ks * 32;
    const int reg = 32768 + (buf * 2 + ks) * 8192;
    async16(src + boff0, &lds[reg + ldsW0]);
    async16(src + boff1, &lds[reg + ldsW1]);
  };

  // read-side swizzle: row = 16*base + lr -> (row>>1)&3 == (lr>>1)&3
  const int laneSwz = (lg ^ ((lr >> 1) & 3)) * 8;
  f32x4 acc[8][4] = {};
  f16x8 af[4], bf[4];

#define LOAD_A(b, ks, mh)                                                     \
  _Pragma("unroll") for (int i = 0; i < 4; ++i) {                             \
    const int row_ = wm * 128 + ((mh) * 4 + i) * 16 + lr;                     \
    af[i] = *reinterpret_cast<const f16x8*>(                                  \
        &lds[((b) * 2 + (ks)) * 8192 + row_ * 32 + laneSwz]);                 \
  }
#define LOAD_B(b, ks)                                                         \
  _Pragma("unroll") for (int i = 0; i < 4; ++i) {                             \
    const int row_ = wn * 64 + i * 16 + lr;                                   \
    bf[i] = *reinterpret_cast<const f16x8*>(                                  \
        &lds[32768 + ((b) * 2 + (ks)) * 8192 + row_ * 32 + laneSwz]);         \
  }
#define MFMA16(mh)                                                            \
  _Pragma("unroll") for (int i = 0; i < 4; ++i)                               \
  _Pragma("unroll") for (int j = 0; j < 4; ++j)                               \
    acc[(mh) * 4 + i][j] = __builtin_amdgcn_mfma_f32_16x16x32_f16(            \
        af[i], bf[j], acc[(mh) * 4 + i][j], 0, 0, 0);
#define WAIT_LGKM()                                       \
  asm volatile("s_waitcnt lgkmcnt(0)" ::: "memory");      \
  __builtin_amdgcn_sched_barrier(0);
#define WAIT_VM8()                                        \
  asm volatile("s_waitcnt vmcnt(8)" ::: "memory");        \
  __builtin_amdgcn_sched_barrier(0);

#define TILE(t, b)                                                            \
  {                                                                           \
    /* P1: k-slice0, m-half0 */                                               \
    LOAD_B(b, 0); LOAD_A(b, 0, 0);                                            \
    stageA((t) + 1, 1, (b) ^ 1);                                              \
    __builtin_amdgcn_s_barrier(); WAIT_LGKM();                                \
    __builtin_amdgcn_s_setprio(1); MFMA16(0); __builtin_amdgcn_s_setprio(0);  \
    __builtin_amdgcn_s_barrier();                                             \
    /* P2: k-slice0, m-half1 */                                               \
    LOAD_A(b, 0, 1);                                                          \
    stageB((t) + 1, 1, (b) ^ 1);                                              \
    __builtin_amdgcn_s_barrier(); WAIT_LGKM();                                \
    __builtin_amdgcn_s_setprio(1); MFMA16(1); __builtin_amdgcn_s_setprio(0);  \
    WAIT_VM8();                                                               \
    __builtin_amdgcn_s_barrier();                                             \
    /* P3: k-slice1, m-half0 */                                               \
    LOAD_B(b, 1); LOAD_A(b, 1, 0);                                            \
    stageA((t) + 2, 0, (b));                                                  \
    __builtin_amdgcn_s_barrier(); WAIT_LGKM();                                \
    __builtin_amdgcn_s_setprio(1); MFMA16(0); __builtin_amdgcn_s_setprio(0);  \
    __builtin_amdgcn_s_barrier();                                             \
    /* P4: k-slice1, m-half1 */                                               \
    LOAD_A(b, 1, 1);                                                          \
    stageB((t) + 2, 0, (b));                                                  \
    __builtin_amdgcn_s_barrier(); WAIT_LGKM();                                \
    __builtin_amdgcn_s_setprio(1); MFMA16(1); __builtin_amdgcn_s_setprio(0);  \
    WAIT_VM8();                                                               \
    __builtin_amdgcn_s_barrier();                                             \
  }

  // prologue: tile0 (all 4 halves) + tile1 k-slice0 = 6 stages (12 loads);
  // vmcnt(8) -> oldest 4 loads (A/B k0 of tile0) landed.
  stageA(0, 0, 0); stageB(0, 0, 0);
  stageA(0, 1, 0); stageB(0, 1, 0);
  stageA(1, 0, 1); stageB(1, 0, 1);
  WAIT_VM8();
  __builtin_amdgcn_s_barrier();

  const int NTE = NT & ~1;
  for (int tp = 0; tp < NTE; tp += 2) {
    TILE(tp, 0);
    TILE(tp + 1, 1);
  }
  if (NT & 1) TILE(NT - 1, 0);   // last tile sits in buf 0 when NT odd

#undef TILE
#undef LOAD_A
#undef LOAD_B
#undef MFMA16
#undef WAIT_LGKM
#undef WAIT_VM8

  uint16_t* Cp = Cc + (long)zb * cBatch + ((long)bx * 256) * ldc + (long)by * 256;
#pragma unroll
  for (int mf = 0; mf < 8; ++mf) {
#pragma unroll
    for (int nf = 0; nf < 4; ++nf) {
      const int col = wn * 64 + nf * 16 + lr;
      const f32x4 v = acc[mf][nf];
#pragma unroll
      for (int qq = 0; qq < 4; ++qq) {
        const int row = wm * 128 + mf * 16 + lg * 4 + qq;
        float val = v[qq];
        if constexpr (BIAS == 1) val += bias[bx * 256 + row];
        if constexpr (BIAS == 2) val += bias[by * 256 + col];
        __builtin_nontemporal_store(f2h(val), &Cp[(long)row * ldc + col]);
      }
    }
  }
}

// ---------------------------------------------------------------------------
// x [C,N] fp32 -> xT [NP,C] fp16 (zero-padded rows n >= N_)
// ---------------------------------------------------------------------------
__global__ __launch_bounds__(256) void transpose_cast(
    const float* __restrict__ x, uint16_t* __restrict__ xT) {
  __shared__ float t[32][33];
  const int b = blockIdx.z;
  const float* xb = x + (long)b * C_ * N_;
  uint16_t* xTb = xT + (long)b * NP * C_;
  const int n0 = blockIdx.x * 32, c0 = blockIdx.y * 32;
  const int tx = threadIdx.x & 31, ty = threadIdx.x >> 5;
#pragma unroll
  for (int i = 0; i < 4; ++i) {
    const int cc = c0 + ty + i * 8, nn = n0 + tx;
    t[ty + i * 8][tx] = (nn < N_) ? xb[(long)cc * N_ + nn] : 0.f;
  }
  __syncthreads();
#pragma unroll
  for (int i = 0; i < 4; ++i) {
    const int nn = n0 + ty + i * 8, cc = c0 + tx;
    __builtin_nontemporal_store(f2h(t[tx][ty + i * 8]), &xTb[(long)nn * C_ + cc]);
  }
}

// one kernel for all 4 weight conversions (saves 3 launch overheads)
__global__ __launch_bounds__(256) void cvt_f16_all(
    const float* __restrict__ s0, uint16_t* __restrict__ d0, int n0,
    const float* __restrict__ s1, uint16_t* __restrict__ d1, int n1,
    const float* __restrict__ s2, uint16_t* __restrict__ d2, int n2,
    const float* __restrict__ s3, uint16_t* __restrict__ d3, int n3) {
  const int stride = gridDim.x * 256;
  const int total = n0 + n1 + n2 + n3;
  for (int i = blockIdx.x * 256 + threadIdx.x; i < total; i += stride) {
    int j = i;
    if (j < n0) { d0[j] = f2h(s0[j]); continue; }
    j -= n0;
    if (j < n1) { d1[j] = f2h(s1[j]); continue; }
    j -= n1;
    if (j < n2) { d2[j] = f2h(s2[j]); continue; }
    j -= n2;
    d3[j] = f2h(s3[j]);
  }
}

__global__ __launch_bounds__(256) void concat_bias(
    const float* __restrict__ a, const float* __restrict__ b,
    float* __restrict__ d) {
  const int i = blockIdx.x * 256 + threadIdx.x;
  if (i < 512) d[i] = a[i];
  else if (i < 1024) d[i] = b[i - 512];
}

// ---------------------------------------------------------------------------
// in-place row softmax on fp16 f [*, NP, NP], valid rows/cols < N_ only.
// blockIdx.x = row (< N_), blockIdx.y = batch. Only cols < N_ rewritten;
// y-GEMM consumes K = N_ so pad cols are never read.
// ---------------------------------------------------------------------------
__global__ __launch_bounds__(256) void softmax_inplace(uint16_t* __restrict__ f) {
  const int row = blockIdx.x, tid = threadIdx.x;
  uint16_t* p = f + ((long)blockIdx.y * NP + row) * NP;
  __shared__ float buf[N_];
  __shared__ float red[8];
  float mx = -3.4e38f;
  for (int ch = tid; ch < N_ / 8; ch += 256) {
    const f16x8 v = *reinterpret_cast<const f16x8*>(p + ch * 8);
#pragma unroll
    for (int j = 0; j < 8; ++j) {
      const float fv = (float)v[j];
      buf[ch * 8 + j] = fv;
      mx = fmaxf(mx, fv);
    }
  }
  for (int o = 32; o; o >>= 1) mx = fmaxf(mx, __shfl_xor(mx, o));
  if ((tid & 63) == 0) red[tid >> 6] = mx;
  __syncthreads();
  mx = fmaxf(fmaxf(red[0], red[1]), fmaxf(red[2], red[3]));

  float s = 0.f;
  for (int i = tid; i < N_; i += 256) {
    const float e = __expf(buf[i] - mx);
    buf[i] = e;
    s += e;
  }
  for (int o = 32; o; o >>= 1) s += __shfl_xor(s, o);
  __syncthreads();
  if ((tid & 63) == 0) red[tid >> 6] = s;
  __syncthreads();
  const float rinv = 1.0f / (red[0] + red[1] + red[2] + red[3]);

  for (int ch = tid; ch < N_ / 8; ch += 256) {
    f16x8 o8;
#pragma unroll
    for (int j = 0; j < 8; ++j) o8[j] = (_Float16)(buf[ch * 8 + j] * rinv);
    __builtin_nontemporal_store(o8, reinterpret_cast<f16x8*>(p + ch * 8));
  }
}

// ---------------------------------------------------------------------------
// BN stats over fp16 z [B][C][NP] (cols < N_ only).
// ---------------------------------------------------------------------------
__global__ __launch_bounds__(256) void bn_stats(
    const _Float16* __restrict__ z, const float* __restrict__ gamma,
    const float* __restrict__ beta, float* __restrict__ ss) {
  const int c = blockIdx.x, tid = threadIdx.x;
  float sum = 0.f, sq = 0.f;
  for (int b = 0; b < B_; ++b) {
    const _Float16* zp = z + ((long)b * C_ + c) * NP;
    for (int ch = tid; ch < N_ / 8; ch += 256) {
      const f16x8 v = *(const f16x8*)(zp + ch * 8);
#pragma unroll
      for (int j = 0; j < 8; ++j) {
        const float fv = (float)v[j];
        sum += fv;
        sq += fv * fv;
      }
    }
  }
  for (int o = 32; o; o >>= 1) {
    sum += __shfl_xor(sum, o);
    sq += __shfl_xor(sq, o);
  }
  __shared__ float r1[8], r2[8];
  if ((tid & 63) == 0) { r1[tid >> 6] = sum; r2[tid >> 6] = sq; }
  __syncthreads();
  if (tid == 0) {
    sum = r1[0] + r1[1] + r1[2] + r1[3];
    sq  = r2[0] + r2[1] + r2[2] + r2[3];
    const float inv_n = 1.0f / (float)(B_ * N_);
    const float mean = sum * inv_n;
    const float var = sq * inv_n - mean * mean;
    const float sc = gamma[c] * rsqrtf(var + BN_EPS);
    ss[c] = sc;
    ss[C_ + c] = beta[c] - mean * sc;
  }
}

__global__ __launch_bounds__(256) void bn_apply(
    const _Float16* __restrict__ z, const float* __restrict__ x,
    const float* __restrict__ ss, float* __restrict__ out) {
  constexpr int CH = N_ / 8;  // 392 8-element chunks per row
  const long nv = (long)B_ * C_ * CH;
  const long stride = (long)gridDim.x * 256;
  for (long v = (long)blockIdx.x * 256 + threadIdx.x; v < nv; v += stride) {
    const long row = v / CH;
    const int ch = (int)(v % CH);
    const int c = (int)(row % C_);
    const f16x8 zz = *(const f16x8*)(z + row * NP + ch * 8);
    const f32x4 x0 = *(const f32x4*)(x + row * (long)N_ + ch * 8);
    const f32x4 x1 = *(const f32x4*)(x + row * (long)N_ + ch * 8 + 4);
    const float sc = ss[c], sh = ss[C_ + c];
    f32x4 o0, o1;
#pragma unroll
    for (int j = 0; j < 4; ++j) o0[j] = (float)zz[j] * sc + sh + x0[j];
#pragma unroll
    for (int j = 0; j < 4; ++j) o1[j] = (float)zz[4 + j] * sc + sh + x1[j];
    __builtin_nontemporal_store(o0, (f32x4*)(out + row * (long)N_ + ch * 8));
    __builtin_nontemporal_store(o1, (f32x4*)(out + row * (long)N_ + ch * 8 + 4));
  }
}

// ---------------------------------------------------------------------------
extern "C" void kernel_launch(void* const* d_in, const int* in_sizes, int n_in,
                              void* d_out, int out_size, void* d_ws,
                              size_t ws_size, hipStream_t stream) {
  const float* x       = (const float*)d_in[0];
  const float* theta_w = (const float*)d_in[1];
  const float* theta_b = (const float*)d_in[2];
  const float* phi_w   = (const float*)d_in[3];
  const float* phi_b   = (const float*)d_in[4];
  const float* g_w     = (const float*)d_in[5];
  const float* g_b     = (const float*)d_in[6];
  const float* wz_w    = (const float*)d_in[7];
  const float* wz_b    = (const float*)d_in[8];
  const float* gamma   = (const float*)d_in[9];
  const float* beta    = (const float*)d_in[10];
  float* out = (float*)d_out;

  char* ws = (char*)d_ws;
  size_t off = 0;
  auto alloc = [&](size_t bytes) {
    void* p = ws + off;
    off += (bytes + 255) & ~(size_t)255;
    return p;
  };
  uint16_t* wfused = (uint16_t*)alloc((size_t)1024 * 1024 * 2);  // theta|phi
  uint16_t* wg     = (uint16_t*)alloc((size_t)CI_ * C_ * 2);
  uint16_t* wzh    = (uint16_t*)alloc((size_t)C_ * CI_ * 2);
  float*    bfused = (float*)alloc((size_t)1024 * 4);
  uint16_t* projT  = (uint16_t*)alloc((size_t)B_ * NP * 1024 * 2);
  uint16_t* gbuf   = (uint16_t*)alloc((size_t)B_ * CI_ * NP * 2);
  uint16_t* ybuf   = (uint16_t*)alloc((size_t)B_ * NP * CI_ * 2);
  uint16_t* zbuf   = (uint16_t*)alloc((size_t)B_ * C_ * NP * 2);
  float*    ss     = (float*)alloc((size_t)C_ * 2 * 4);

  // xT and f share one region (xT dead once proj+g GEMMs have run).
  const size_t xTb = (size_t)B_ * NP * C_ * 2;
  const size_t fB  = (size_t)B_ * NP * NP * 2;
  uint16_t* xT    = (uint16_t*)alloc(fB > xTb ? fB : xTb);
  uint16_t* fattn = xT;
  if (off > ws_size) {
    fprintf(stderr, "kernel_launch: workspace too small: need %zu have %zu\n",
            off, ws_size);
    return;
  }

  // weights -> fp16 (single kernel)
  cvt_f16_all<<<512, 256, 0, stream>>>(
      theta_w, wfused, CI_ * C_,
      phi_w, wfused + 512 * 1024, CI_ * C_,
      g_w, wg, CI_ * C_,
      wz_w, wzh, C_ * CI_);
  concat_bias<<<4, 256, 0, stream>>>(theta_b, phi_b, bfused);

  // x -> xT fp16 [B, NP, C]
  transpose_cast<<<dim3(NP / 32, C_ / 32, B_), 256, 0, stream>>>(x, xT);

  // projT[b*NP+n, o] = xT.wfused + bfused[o]  (o<512: theta, >=512: phi)
  // colMajor=1: consecutive blocks share the xT A-panel (L2 reuse)
  gemm256<2><<<dim3(B_ * NP / 256 * 4), 512, 0, stream>>>(
      xT, wfused, projT, bfused, C_, C_, C_, 1024,
      0, 0, 0, B_ * NP / 256, 4, 1);
  // gbuf[b][ci][n] = wg[ci,:].xT[b,n,:] + g_b[ci]  (rowMajor: xT B-panel
  // shared by the 2 consecutive bx blocks)
  gemm256<1><<<dim3(2 * 13 * B_), 512, 0, stream>>>(
      wg, xT, gbuf, g_b, C_, C_, C_, NP,
      0, (long)NP * C_, (long)CI_ * NP, 2, 13, 0);

  // f[n,m] = theta_n . phi_m  (fp16, in-place softmax next); rowMajor:
  // B-panel (262KB) reused across 13 consecutive blocks, A panels (3.4MB)
  // cycle within L2 now that C-writes bypass L2.
  gemm256<0><<<dim3(13 * 13 * B_), 512, 0, stream>>>(
      projT, projT + 512, fattn, nullptr, CI_, 1024, 1024, NP,
      (long)NP * 1024, (long)NP * 1024, (long)NP * NP, 13, 13, 0);
  softmax_inplace<<<dim3(N_, B_), 256, 0, stream>>>(fattn);

  // y[n,ci] = sum_{m<N_} attn[n,m]*gbuf[ci,m]; K=3136 (NT=49, odd tail)
  // colMajor=1: the 2 CI-blocks sharing an attn A-panel run back-to-back.
  gemm256<0><<<dim3(13 * 2 * B_), 512, 0, stream>>>(
      fattn, gbuf, ybuf, nullptr, N_, NP, NP, CI_,
      (long)NP * NP, (long)CI_ * NP, (long)NP * CI_, 13, 2, 1);

  // z[c,n] = wz[c,:].y[n,:] + wz_b[c]  (fp16); rowMajor: ybuf B-panel shared
  // by 4 consecutive bx blocks, wzh (1MB) L2-resident.
  gemm256<1><<<dim3(4 * 13 * B_), 512, 0, stream>>>(
      wzh, ybuf, zbuf, wz_b, CI_, CI_, CI_, NP,
      0, (long)NP * CI_, (long)C_ * NP, 4, 13, 0);

  bn_stats<<<C_, 256, 0, stream>>>((const _Float16*)zbuf, gamma, beta, ss);
  bn_apply<<<4096, 256, 0, stream>>>((const _Float16*)zbuf, x, ss, out);
}

// Round 9
// 507.852 us; speedup vs baseline: 1.1674x; 1.1674x over previous
//
#include <hip/hip_runtime.h>
#include <cstdint>
#include <cstdio>

#define DEVINL __device__ __forceinline__

typedef _Float16 f16x8 __attribute__((ext_vector_type(8)));
typedef float    f32x4 __attribute__((ext_vector_type(4)));

static constexpr int B_  = 8;
static constexpr int C_  = 1024;
static constexpr int CI_ = 512;
static constexpr int N_  = 56 * 56;   // 3136
static constexpr int NP  = 3328;      // padded to multiple of 256
static constexpr float BN_EPS = 1e-5f;

DEVINL uint16_t f2h(float f) {
  union { _Float16 h; uint16_t u; } cv;
  cv.h = (_Float16)f;   // RNE
  return cv.u;
}

DEVINL void async16(const void* g, void* lds) {
  __builtin_amdgcn_global_load_lds(
      (const __attribute__((address_space(1))) uint32_t*)g,
      (__attribute__((address_space(3))) uint32_t*)lds, 16, 0, 0);
}

// ---------------------------------------------------------------------------
// 256x256 8-phase TN GEMM (m201 template, fp16 in / fp16 out, fp32 acc).
// C[m,n] = sum_k A[m,k]*Bt[n,k] (+bias). M%256==0, N%256==0, K%64==0.
// 512 threads = 8 waves (2M x 4N); per-wave output 128x64; acc[8][4] f32x4.
// LDS 128KB: A/B x 2 bufs x 2 k-slices(32) of [256][32] fp16.
// Swizzle: 16B chunk c within row: phys = c ^ ((row>>1)&3) (both sides;
// verified r5: bank conflicts 8.3M -> 0). Counted vmcnt(8) only; per-phase
// barrier + lgkmcnt(0) + sched_barrier(0). BIAS: 0 none, 1 per-row, 2 per-col.
// colMajor: 1 -> by varies fastest over consecutive wgid (A-panel reuse;
// verified r8: FETCH 95 -> 57 MB on the f-GEMM).
// C stores are NORMAL cached stores: epilogue writes are 2B-scattered per
// lane; NT partial-line streaming caused 1.39x write amplification (r8).
// ---------------------------------------------------------------------------
template <int BIAS>
__global__ __launch_bounds__(512, 2) void gemm256(
    const uint16_t* __restrict__ A, const uint16_t* __restrict__ Bt,
    uint16_t* __restrict__ Cc, const float* __restrict__ bias,
    int K, int lda, int ldb, int ldc,
    long aBatch, long bBatch, long cBatch, int nbx, int nby, int colMajor) {
  __shared__ uint16_t lds[65536];   // 128 KiB

  // bijective XCD swizzle (m204)
  const int nwg = gridDim.x, orig = blockIdx.x;
  const int q = nwg >> 3, r = nwg & 7, xcd = orig & 7, idx = orig >> 3;
  const int wgid = (xcd < r ? xcd * (q + 1) : r * (q + 1) + (xcd - r) * q) + idx;
  const int rest = wgid % (nbx * nby);
  const int bx = colMajor ? rest / nby : rest % nbx;
  const int by = colMajor ? rest % nby : rest / nbx;
  const int zb = wgid / (nbx * nby);

  const int tid = threadIdx.x, w = tid >> 6, l = tid & 63;
  const int wm = w >> 2, wn = w & 3, lr = l & 15, lg = l >> 4;

  const uint16_t* Ab = A + (long)zb * aBatch + (long)bx * 256 * lda;
  const uint16_t* Bb = Bt + (long)zb * bBatch + (long)by * 256 * ldb;

  const int NT = K >> 6;

  // staging: half-tile = [256 rows][32 k] fp16 = 1024 chunks of 16B, 2 instrs.
  // chunk c: row=c>>2, source col pre-swizzled: col16 = (c&3) ^ ((c>>3)&3)
  const int c0 = tid, c1 = 512 + tid;
  const long aoff0 = (long)(c0 >> 2) * lda + (((c0 & 3) ^ ((c0 >> 3) & 3)) * 8);
  const long aoff1 = (long)(c1 >> 2) * lda + (((c1 & 3) ^ ((c1 >> 3) & 3)) * 8);
  const long boff0 = (long)(c0 >> 2) * ldb + (((c0 & 3) ^ ((c0 >> 3) & 3)) * 8);
  const long boff1 = (long)(c1 >> 2) * ldb + (((c1 & 3) ^ ((c1 >> 3) & 3)) * 8);
  const int ldsW0 = (w * 64) * 8;          // wave-uniform dest (elems), instr 0
  const int ldsW1 = (512 + w * 64) * 8;    // instr 1

  auto stageA = [&](int t, int ks, int buf) {
    int tw = t; while (tw >= NT) tw -= NT;   // wrap: garbage, never computed
    const uint16_t* src = Ab + tw * 64 + ks * 32;
    const int reg = (buf * 2 + ks) * 8192;
    async16(src + aoff0, &lds[reg + ldsW0]);
    async16(src + aoff1, &lds[reg + ldsW1]);
  };
  auto stageB = [&](int t, int ks, int buf) {
    int tw = t; while (tw >= NT) tw -= NT;
    const uint16_t* src = Bb + tw * 64 + ks * 32;
    const int reg = 32768 + (buf * 2 + ks) * 8192;
    async16(src + boff0, &lds[reg + ldsW0]);
    async16(src + boff1, &lds[reg + ldsW1]);
  };

  // read-side swizzle: row = 16*base + lr -> (row>>1)&3 == (lr>>1)&3
  const int laneSwz = (lg ^ ((lr >> 1) & 3)) * 8;
  f32x4 acc[8][4] = {};
  f16x8 af[4], bf[4];

#define LOAD_A(b, ks, mh)                                                     \
  _Pragma("unroll") for (int i = 0; i < 4; ++i) {                             \
    const int row_ = wm * 128 + ((mh) * 4 + i) * 16 + lr;                     \
    af[i] = *reinterpret_cast<const f16x8*>(                                  \
        &lds[((b) * 2 + (ks)) * 8192 + row_ * 32 + laneSwz]);                 \
  }
#define LOAD_B(b, ks)                                                         \
  _Pragma("unroll") for (int i = 0; i < 4; ++i) {                             \
    const int row_ = wn * 64 + i * 16 + lr;                                   \
    bf[i] = *reinterpret_cast<const f16x8*>(                                  \
        &lds[32768 + ((b) * 2 + (ks)) * 8192 + row_ * 32 + laneSwz]);         \
  }
#define MFMA16(mh)                                                            \
  _Pragma("unroll") for (int i = 0; i < 4; ++i)                               \
  _Pragma("unroll") for (int j = 0; j < 4; ++j)                               \
    acc[(mh) * 4 + i][j] = __builtin_amdgcn_mfma_f32_16x16x32_f16(            \
        af[i], bf[j], acc[(mh) * 4 + i][j], 0, 0, 0);
#define WAIT_LGKM()                                       \
  asm volatile("s_waitcnt lgkmcnt(0)" ::: "memory");      \
  __builtin_amdgcn_sched_barrier(0);
#define WAIT_VM8()                                        \
  asm volatile("s_waitcnt vmcnt(8)" ::: "memory");        \
  __builtin_amdgcn_sched_barrier(0);

#define TILE(t, b)                                                            \
  {                                                                           \
    /* P1: k-slice0, m-half0 */                                               \
    LOAD_B(b, 0); LOAD_A(b, 0, 0);                                            \
    stageA((t) + 1, 1, (b) ^ 1);                                              \
    __builtin_amdgcn_s_barrier(); WAIT_LGKM();                                \
    __builtin_amdgcn_s_setprio(1); MFMA16(0); __builtin_amdgcn_s_setprio(0);  \
    __builtin_amdgcn_s_barrier();                                             \
    /* P2: k-slice0, m-half1 */                                               \
    LOAD_A(b, 0, 1);                                                          \
    stageB((t) + 1, 1, (b) ^ 1);                                              \
    __builtin_amdgcn_s_barrier(); WAIT_LGKM();                                \
    __builtin_amdgcn_s_setprio(1); MFMA16(1); __builtin_amdgcn_s_setprio(0);  \
    WAIT_VM8();                                                               \
    __builtin_amdgcn_s_barrier();                                             \
    /* P3: k-slice1, m-half0 */                                               \
    LOAD_B(b, 1); LOAD_A(b, 1, 0);                                            \
    stageA((t) + 2, 0, (b));                                                  \
    __builtin_amdgcn_s_barrier(); WAIT_LGKM();                                \
    __builtin_amdgcn_s_setprio(1); MFMA16(0); __builtin_amdgcn_s_setprio(0);  \
    __builtin_amdgcn_s_barrier();                                             \
    /* P4: k-slice1, m-half1 */                                               \
    LOAD_A(b, 1, 1);                                                          \
    stageB((t) + 2, 0, (b));                                                  \
    __builtin_amdgcn_s_barrier(); WAIT_LGKM();                                \
    __builtin_amdgcn_s_setprio(1); MFMA16(1); __builtin_amdgcn_s_setprio(0);  \
    WAIT_VM8();                                                               \
    __builtin_amdgcn_s_barrier();                                             \
  }

  // prologue: tile0 (all 4 halves) + tile1 k-slice0 = 6 stages (12 loads);
  // vmcnt(8) -> oldest 4 loads (A/B k0 of tile0) landed.
  stageA(0, 0, 0); stageB(0, 0, 0);
  stageA(0, 1, 0); stageB(0, 1, 0);
  stageA(1, 0, 1); stageB(1, 0, 1);
  WAIT_VM8();
  __builtin_amdgcn_s_barrier();

  const int NTE = NT & ~1;
  for (int tp = 0; tp < NTE; tp += 2) {
    TILE(tp, 0);
    TILE(tp + 1, 1);
  }
  if (NT & 1) TILE(NT - 1, 0);   // last tile sits in buf 0 when NT odd

#undef TILE
#undef LOAD_A
#undef LOAD_B
#undef MFMA16
#undef WAIT_LGKM
#undef WAIT_VM8

  uint16_t* Cp = Cc + (long)zb * cBatch + ((long)bx * 256) * ldc + (long)by * 256;
#pragma unroll
  for (int mf = 0; mf < 8; ++mf) {
#pragma unroll
    for (int nf = 0; nf < 4; ++nf) {
      const int col = wn * 64 + nf * 16 + lr;
      const f32x4 v = acc[mf][nf];
#pragma unroll
      for (int qq = 0; qq < 4; ++qq) {
        const int row = wm * 128 + mf * 16 + lg * 4 + qq;
        float val = v[qq];
        if constexpr (BIAS == 1) val += bias[bx * 256 + row];
        if constexpr (BIAS == 2) val += bias[by * 256 + col];
        Cp[(long)row * ldc + col] = f2h(val);
      }
    }
  }
}

// ---------------------------------------------------------------------------
// x [C,N] fp32 -> xT [NP,C] fp16 (zero-padded rows n >= N_)
// ---------------------------------------------------------------------------
__global__ __launch_bounds__(256) void transpose_cast(
    const float* __restrict__ x, uint16_t* __restrict__ xT) {
  __shared__ float t[32][33];
  const int b = blockIdx.z;
  const float* xb = x + (long)b * C_ * N_;
  uint16_t* xTb = xT + (long)b * NP * C_;
  const int n0 = blockIdx.x * 32, c0 = blockIdx.y * 32;
  const int tx = threadIdx.x & 31, ty = threadIdx.x >> 5;
#pragma unroll
  for (int i = 0; i < 4; ++i) {
    const int cc = c0 + ty + i * 8, nn = n0 + tx;
    t[ty + i * 8][tx] = (nn < N_) ? xb[(long)cc * N_ + nn] : 0.f;
  }
  __syncthreads();
#pragma unroll
  for (int i = 0; i < 4; ++i) {
    const int nn = n0 + ty + i * 8, cc = c0 + tx;
    xTb[(long)nn * C_ + cc] = f2h(t[tx][ty + i * 8]);
  }
}

// one kernel for all 4 weight conversions (saves 3 launch overheads)
__global__ __launch_bounds__(256) void cvt_f16_all(
    const float* __restrict__ s0, uint16_t* __restrict__ d0, int n0,
    const float* __restrict__ s1, uint16_t* __restrict__ d1, int n1,
    const float* __restrict__ s2, uint16_t* __restrict__ d2, int n2,
    const float* __restrict__ s3, uint16_t* __restrict__ d3, int n3) {
  const int stride = gridDim.x * 256;
  const int total = n0 + n1 + n2 + n3;
  for (int i = blockIdx.x * 256 + threadIdx.x; i < total; i += stride) {
    int j = i;
    if (j < n0) { d0[j] = f2h(s0[j]); continue; }
    j -= n0;
    if (j < n1) { d1[j] = f2h(s1[j]); continue; }
    j -= n1;
    if (j < n2) { d2[j] = f2h(s2[j]); continue; }
    j -= n2;
    d3[j] = f2h(s3[j]);
  }
}

__global__ __launch_bounds__(256) void concat_bias(
    const float* __restrict__ a, const float* __restrict__ b,
    float* __restrict__ d) {
  const int i = blockIdx.x * 256 + threadIdx.x;
  if (i < 512) d[i] = a[i];
  else if (i < 1024) d[i] = b[i - 512];
}

// ---------------------------------------------------------------------------
// in-place row softmax on fp16 f [*, NP, NP], valid rows/cols < N_ only.
// blockIdx.x = row (< N_), blockIdx.y = batch. Only cols < N_ rewritten;
// y-GEMM consumes K = N_ so pad cols are never read.
// ---------------------------------------------------------------------------
__global__ __launch_bounds__(256) void softmax_inplace(uint16_t* __restrict__ f) {
  const int row = blockIdx.x, tid = threadIdx.x;
  uint16_t* p = f + ((long)blockIdx.y * NP + row) * NP;
  __shared__ float buf[N_];
  __shared__ float red[8];
  float mx = -3.4e38f;
  for (int ch = tid; ch < N_ / 8; ch += 256) {
    const f16x8 v = *reinterpret_cast<const f16x8*>(p + ch * 8);
#pragma unroll
    for (int j = 0; j < 8; ++j) {
      const float fv = (float)v[j];
      buf[ch * 8 + j] = fv;
      mx = fmaxf(mx, fv);
    }
  }
  for (int o = 32; o; o >>= 1) mx = fmaxf(mx, __shfl_xor(mx, o));
  if ((tid & 63) == 0) red[tid >> 6] = mx;
  __syncthreads();
  mx = fmaxf(fmaxf(red[0], red[1]), fmaxf(red[2], red[3]));

  float s = 0.f;
  for (int i = tid; i < N_; i += 256) {
    const float e = __expf(buf[i] - mx);
    buf[i] = e;
    s += e;
  }
  for (int o = 32; o; o >>= 1) s += __shfl_xor(s, o);
  __syncthreads();
  if ((tid & 63) == 0) red[tid >> 6] = s;
  __syncthreads();
  const float rinv = 1.0f / (red[0] + red[1] + red[2] + red[3]);

  for (int ch = tid; ch < N_ / 8; ch += 256) {
    f16x8 o8;
#pragma unroll
    for (int j = 0; j < 8; ++j) o8[j] = (_Float16)(buf[ch * 8 + j] * rinv);
    *reinterpret_cast<f16x8*>(p + ch * 8) = o8;
  }
}

// ---------------------------------------------------------------------------
// BN stats over fp16 z [B][C][NP] (cols < N_ only).
// ---------------------------------------------------------------------------
__global__ __launch_bounds__(256) void bn_stats(
    const _Float16* __restrict__ z, const float* __restrict__ gamma,
    const float* __restrict__ beta, float* __restrict__ ss) {
  const int c = blockIdx.x, tid = threadIdx.x;
  float sum = 0.f, sq = 0.f;
  for (int b = 0; b < B_; ++b) {
    const _Float16* zp = z + ((long)b * C_ + c) * NP;
    for (int ch = tid; ch < N_ / 8; ch += 256) {
      const f16x8 v = *(const f16x8*)(zp + ch * 8);
#pragma unroll
      for (int j = 0; j < 8; ++j) {
        const float fv = (float)v[j];
        sum += fv;
        sq += fv * fv;
      }
    }
  }
  for (int o = 32; o; o >>= 1) {
    sum += __shfl_xor(sum, o);
    sq += __shfl_xor(sq, o);
  }
  __shared__ float r1[8], r2[8];
  if ((tid & 63) == 0) { r1[tid >> 6] = sum; r2[tid >> 6] = sq; }
  __syncthreads();
  if (tid == 0) {
    sum = r1[0] + r1[1] + r1[2] + r1[3];
    sq  = r2[0] + r2[1] + r2[2] + r2[3];
    const float inv_n = 1.0f / (float)(B_ * N_);
    const float mean = sum * inv_n;
    const float var = sq * inv_n - mean * mean;
    const float sc = gamma[c] * rsqrtf(var + BN_EPS);
    ss[c] = sc;
    ss[C_ + c] = beta[c] - mean * sc;
  }
}

__global__ __launch_bounds__(256) void bn_apply(
    const _Float16* __restrict__ z, const float* __restrict__ x,
    const float* __restrict__ ss, float* __restrict__ out) {
  constexpr int CH = N_ / 8;  // 392 8-element chunks per row
  const long nv = (long)B_ * C_ * CH;
  const long stride = (long)gridDim.x * 256;
  for (long v = (long)blockIdx.x * 256 + threadIdx.x; v < nv; v += stride) {
    const long row = v / CH;
    const int ch = (int)(v % CH);
    const int c = (int)(row % C_);
    const f16x8 zz = *(const f16x8*)(z + row * NP + ch * 8);
    const f32x4 x0 = *(const f32x4*)(x + row * (long)N_ + ch * 8);
    const f32x4 x1 = *(const f32x4*)(x + row * (long)N_ + ch * 8 + 4);
    const float sc = ss[c], sh = ss[C_ + c];
    f32x4 o0, o1;
#pragma unroll
    for (int j = 0; j < 4; ++j) o0[j] = (float)zz[j] * sc + sh + x0[j];
#pragma unroll
    for (int j = 0; j < 4; ++j) o1[j] = (float)zz[4 + j] * sc + sh + x1[j];
    // NT is safe ONLY here: 16B/lane contiguous -> full 64B lines, final
    // output never re-read (r8 lesson: NT on scattered 2B stores = 1.39x
    // write amplification).
    __builtin_nontemporal_store(o0, (f32x4*)(out + row * (long)N_ + ch * 8));
    __builtin_nontemporal_store(o1, (f32x4*)(out + row * (long)N_ + ch * 8 + 4));
  }
}

// ---------------------------------------------------------------------------
extern "C" void kernel_launch(void* const* d_in, const int* in_sizes, int n_in,
                              void* d_out, int out_size, void* d_ws,
                              size_t ws_size, hipStream_t stream) {
  const float* x       = (const float*)d_in[0];
  const float* theta_w = (const float*)d_in[1];
  const float* theta_b = (const float*)d_in[2];
  const float* phi_w   = (const float*)d_in[3];
  const float* phi_b   = (const float*)d_in[4];
  const float* g_w     = (const float*)d_in[5];
  const float* g_b     = (const float*)d_in[6];
  const float* wz_w    = (const float*)d_in[7];
  const float* wz_b    = (const float*)d_in[8];
  const float* gamma   = (const float*)d_in[9];
  const float* beta    = (const float*)d_in[10];
  float* out = (float*)d_out;

  char* ws = (char*)d_ws;
  size_t off = 0;
  auto alloc = [&](size_t bytes) {
    void* p = ws + off;
    off += (bytes + 255) & ~(size_t)255;
    return p;
  };
  uint16_t* wfused = (uint16_t*)alloc((size_t)1024 * 1024 * 2);  // theta|phi
  uint16_t* wg     = (uint16_t*)alloc((size_t)CI_ * C_ * 2);
  uint16_t* wzh    = (uint16_t*)alloc((size_t)C_ * CI_ * 2);
  float*    bfused = (float*)alloc((size_t)1024 * 4);
  uint16_t* projT  = (uint16_t*)alloc((size_t)B_ * NP * 1024 * 2);
  uint16_t* gbuf   = (uint16_t*)alloc((size_t)B_ * CI_ * NP * 2);
  uint16_t* ybuf   = (uint16_t*)alloc((size_t)B_ * NP * CI_ * 2);
  uint16_t* zbuf   = (uint16_t*)alloc((size_t)B_ * C_ * NP * 2);
  float*    ss     = (float*)alloc((size_t)C_ * 2 * 4);

  // xT and f share one region (xT dead once proj+g GEMMs have run).
  const size_t xTb = (size_t)B_ * NP * C_ * 2;
  const size_t fB  = (size_t)B_ * NP * NP * 2;
  uint16_t* xT    = (uint16_t*)alloc(fB > xTb ? fB : xTb);
  uint16_t* fattn = xT;
  if (off > ws_size) {
    fprintf(stderr, "kernel_launch: workspace too small: need %zu have %zu\n",
            off, ws_size);
    return;
  }

  // weights -> fp16 (single kernel)
  cvt_f16_all<<<512, 256, 0, stream>>>(
      theta_w, wfused, CI_ * C_,
      phi_w, wfused + 512 * 1024, CI_ * C_,
      g_w, wg, CI_ * C_,
      wz_w, wzh, C_ * CI_);
  concat_bias<<<4, 256, 0, stream>>>(theta_b, phi_b, bfused);

  // x -> xT fp16 [B, NP, C]
  transpose_cast<<<dim3(NP / 32, C_ / 32, B_), 256, 0, stream>>>(x, xT);

  // projT[b*NP+n, o] = xT.wfused + bfused[o]  (o<512: theta, >=512: phi)
  // colMajor=1: consecutive blocks share the xT A-panel (L2 reuse)
  gemm256<2><<<dim3(B_ * NP / 256 * 4), 512, 0, stream>>>(
      xT, wfused, projT, bfused, C_, C_, C_, 1024,
      0, 0, 0, B_ * NP / 256, 4, 1);
  // gbuf[b][ci][n] = wg[ci,:].xT[b,n,:] + g_b[ci]  (rowMajor: xT B-panel
  // shared by the 2 consecutive bx blocks)
  gemm256<1><<<dim3(2 * 13 * B_), 512, 0, stream>>>(
      wg, xT, gbuf, g_b, C_, C_, C_, NP,
      0, (long)NP * C_, (long)CI_ * NP, 2, 13, 0);

  // f[n,m] = theta_n . phi_m  (fp16, in-place softmax next); rowMajor:
  // B-panel (262KB) reused across 13 consecutive blocks.
  gemm256<0><<<dim3(13 * 13 * B_), 512, 0, stream>>>(
      projT, projT + 512, fattn, nullptr, CI_, 1024, 1024, NP,
      (long)NP * 1024, (long)NP * 1024, (long)NP * NP, 13, 13, 0);
  softmax_inplace<<<dim3(N_, B_), 256, 0, stream>>>(fattn);

  // y[n,ci] = sum_{m<N_} attn[n,m]*gbuf[ci,m]; K=3136 (NT=49, odd tail)
  // colMajor=1: the 2 CI-blocks sharing an attn A-panel run back-to-back.
  gemm256<0><<<dim3(13 * 2 * B_), 512, 0, stream>>>(
      fattn, gbuf, ybuf, nullptr, N_, NP, NP, CI_,
      (long)NP * NP, (long)CI_ * NP, (long)NP * CI_, 13, 2, 1);

  // z[c,n] = wz[c,:].y[n,:] + wz_b[c]  (fp16); rowMajor: ybuf B-panel shared
  // by 4 consecutive bx blocks, wzh (1MB) L2-resident.
  gemm256<1><<<dim3(4 * 13 * B_), 512, 0, stream>>>(
      wzh, ybuf, zbuf, wz_b, CI_, CI_, CI_, NP,
      0, (long)NP * CI_, (long)C_ * NP, 4, 13, 0);

  bn_stats<<<C_, 256, 0, stream>>>((const _Float16*)zbuf, gamma, beta, ss);
  bn_apply<<<4096, 256, 0, stream>>>((const _Float16*)zbuf, x, ss, out);
}